// Round 1
// baseline (16862.955 us; speedup 1.0000x reference)
//
#include <hip/hip_runtime.h>
#include <hip/hip_bf16.h>

typedef __attribute__((ext_vector_type(8))) short short8;
typedef __attribute__((ext_vector_type(8))) unsigned short ushort8;
typedef __attribute__((ext_vector_type(4))) float f32x4;

#define NB 256      // batch rows
#define NS 256      // timesteps
#define NH 512      // hidden/state dim (D == H == 512)
#define NOUT 128
#define XROW 513    // x last-dim stride

#define NCL 16      // clusters
#define RPC 16      // rows per cluster
#define BPC 4       // blocks per cluster
#define UBS 128     // u-dims per block
#define LPAD 520    // padded LDS row length (bf16 elems): 1040B stride -> 2-way bank alias (free)

// ---- workspace layout (bytes) ----
#define OFF_DTS   0                                  // 256 f32 (255 dts + sum_dt)
#define OFF_Y0    4096                               // 256*512 f32
#define OFF_U0    (OFF_Y0 + NB*NH*4)                 // 256*512 f32
#define OFF_M     (OFF_U0 + NB*NH*4)                 // 512*512 bf16
#define OFF_C     (OFF_M + NH*NH*2)                  // 512 f32 (c = W1@b2)
#define OFF_P     (OFF_C + 4096)                     // 128*512 f32 (P = Wout@W2)
#define OFF_HG    (OFF_P + NOUT*NH*4)                // 16*2*16*512 bf16 h exchange
#define OFF_HACC  (OFF_HG + NCL*2*RPC*NH*2)          // 256*512 f32
#define OFF_FLAGS (OFF_HACC + NB*NH*4)               // 16*1024 u32

// -------------------- small prep kernels --------------------

__global__ void k_dts(const float* __restrict__ x, float* __restrict__ dts) {
  int s = threadIdx.x;
  if (s < NS - 1) dts[s] = x[(s + 1) * XROW] - x[s * XROW];
  if (s == NS - 1) dts[NS - 1] = x[(NS - 1) * XROW] - x[0];  // sum_dt (telescoping)
}

__global__ void k_y0(const float* __restrict__ x, float* __restrict__ y0) {
  int b = blockIdx.x;
  const float* src = x + (size_t)b * NS * XROW + (size_t)(NS - 1) * XROW + 1;
  for (int d = threadIdx.x; d < NH; d += blockDim.x) y0[b * NH + d] = src[d];
}

__global__ void k_c(const float* __restrict__ W1, const float* __restrict__ b2,
                    float* __restrict__ c) {
  int i = blockIdx.x * blockDim.x + threadIdx.x;
  if (i < NH) {
    float s = 0.f;
    for (int d = 0; d < NH; ++d) s += W1[i * NH + d] * b2[d];
    c[i] = s;
  }
}

// C[m][n] = sum_k A[m][k]*B[k][n], bf16 out
__global__ void k_mm_nn_bf16(const float* __restrict__ A, const float* __restrict__ Bm,
                             __hip_bfloat16* __restrict__ C, int N, int K) {
  __shared__ float As[16][17], Bs[16][17];
  int tx = threadIdx.x & 15, ty = threadIdx.x >> 4;
  int m = blockIdx.y * 16 + ty, n = blockIdx.x * 16 + tx;
  float acc = 0.f;
  for (int k0 = 0; k0 < K; k0 += 16) {
    As[ty][tx] = A[m * K + k0 + tx];
    Bs[ty][tx] = Bm[(size_t)(k0 + ty) * N + n];
    __syncthreads();
#pragma unroll
    for (int kk = 0; kk < 16; ++kk) acc += As[ty][kk] * Bs[kk][tx];
    __syncthreads();
  }
  C[m * N + n] = __float2bfloat16(acc);
}

// C[m][n] = sum_k A[m][k]*B[k][n], f32 out
__global__ void k_mm_nn_f32(const float* __restrict__ A, const float* __restrict__ Bm,
                            float* __restrict__ C, int N, int K) {
  __shared__ float As[16][17], Bs[16][17];
  int tx = threadIdx.x & 15, ty = threadIdx.x >> 4;
  int m = blockIdx.y * 16 + ty, n = blockIdx.x * 16 + tx;
  float acc = 0.f;
  for (int k0 = 0; k0 < K; k0 += 16) {
    As[ty][tx] = A[m * K + k0 + tx];
    Bs[ty][tx] = Bm[(size_t)(k0 + ty) * N + n];
    __syncthreads();
#pragma unroll
    for (int kk = 0; kk < 16; ++kk) acc += As[ty][kk] * Bs[kk][tx];
    __syncthreads();
  }
  C[m * N + n] = acc;
}

// C[m][n] = sum_k A[m][k]*B[n][k]  (both row-major over k), f32 out
__global__ void k_mm_nt_f32(const float* __restrict__ A, const float* __restrict__ Bm,
                            float* __restrict__ C, int N, int K) {
  __shared__ float As[16][17], Bs[16][17];
  int tx = threadIdx.x & 15, ty = threadIdx.x >> 4;
  int m = blockIdx.y * 16 + ty;
  int n0 = blockIdx.x * 16;
  float acc = 0.f;
  for (int k0 = 0; k0 < K; k0 += 16) {
    As[ty][tx] = A[m * K + k0 + tx];
    Bs[ty][tx] = Bm[(size_t)(n0 + ty) * K + k0 + tx];
    __syncthreads();
#pragma unroll
    for (int kk = 0; kk < 16; ++kk) acc += As[ty][kk] * Bs[tx][kk];
    __syncthreads();
  }
  C[m * N + n0 + tx] = acc;
}

// -------------------- main ODE integration kernel --------------------
// 64 blocks = 16 clusters x 4 blocks. Cluster c owns rows [16c,16c+16);
// block j of a cluster owns u-dims [128j,128j+128) and holds that M-slice in LDS.
// Per RK4 stage: h = tanh(v+b1) locally, exchange h via global + flag barrier,
// then w = M_slice @ h via MFMA 16x16x32 bf16.

__global__ __launch_bounds__(256) void k_main(
    const float* __restrict__ u0, const __hip_bfloat16* __restrict__ Mg,
    const float* __restrict__ cg, const float* __restrict__ b1g,
    const float* __restrict__ dtsg,
    __hip_bfloat16* __restrict__ hG, float* __restrict__ Hacc,
    unsigned int* __restrict__ flags)
{
  __shared__ __hip_bfloat16 Mlds[UBS][LPAD];   // 130 KB
  __shared__ __hip_bfloat16 hlds[RPC][LPAD];   // 16.25 KB
  __shared__ float dtl[NS];

  const int tid = threadIdx.x;
  const int bx = blockIdx.x;
  const int cl = bx >> 2, jb = bx & 3;
  const int lane = tid & 63, wv = tid >> 6;
  const int r = lane & 15, g4 = lane >> 4;
  const int row0 = cl * RPC;
  const int ub = jb * UBS;

  // stage M slice into LDS (rows [ub, ub+128) of M)
  for (int i = tid; i < UBS * 64; i += 256) {
    int row = i >> 6, ch = (i & 63) * 8;
    *(ushort8*)&Mlds[row][ch] = *(const ushort8*)(Mg + (size_t)(ub + row) * NH + ch);
  }
  if (tid < NS) dtl[tid] = dtsg[tid];

  // per-lane state: lane l, reg j, tile t -> (udim = ub + wv*32 + t*16 + g4*4 + j, row = r)
  const int udl0 = wv * 32 + g4 * 4;
  float u[2][4], Wa[2][4], Hs[2][4], Ht[2][4], hr[2][4], wp[2][4];
  float b1r[2][4], cr[2][4];
#pragma unroll
  for (int t = 0; t < 2; ++t)
#pragma unroll
    for (int j = 0; j < 4; ++j) {
      int ud = ub + udl0 + t * 16 + j;
      u[t][j] = u0[(row0 + r) * NH + ud];
      b1r[t][j] = b1g[ud];
      cr[t][j] = cg[ud];
      Ht[t][j] = 0.f;
      wp[t][j] = 0.f;
      Wa[t][j] = 0.f;
      Hs[t][j] = 0.f;
    }
  __syncthreads();

  unsigned int* flg = flags + cl * 1024;
  int sidx = 0;
  for (int step = 0; step < NS - 1; ++step) {
    float dt = dtl[step];
#pragma unroll 1
    for (int st = 0; st < 4; ++st, ++sidx) {
      float gam = (st == 0) ? 0.f : ((st == 3) ? dt : 0.5f * dt);
      // h = tanh(u + gam*w_prev + b1)
#pragma unroll
      for (int t = 0; t < 2; ++t)
#pragma unroll
        for (int j = 0; j < 4; ++j)
          hr[t][j] = tanhf(u[t][j] + gam * wp[t][j] + b1r[t][j]);

      // publish h slice
      int par = sidx & 1;
      __hip_bfloat16* hgp = hG + (size_t)(cl * 2 + par) * RPC * NH;
#pragma unroll
      for (int t = 0; t < 2; ++t)
#pragma unroll
        for (int j = 0; j < 4; ++j)
          hgp[r * NH + ub + udl0 + t * 16 + j] = __float2bfloat16(hr[t][j]);
      __threadfence();
      __syncthreads();
      if (tid == 0) {
        __hip_atomic_fetch_add(&flg[sidx], 1u, __ATOMIC_RELEASE, __HIP_MEMORY_SCOPE_AGENT);
        while (__hip_atomic_load(&flg[sidx], __ATOMIC_ACQUIRE, __HIP_MEMORY_SCOPE_AGENT) < BPC)
          __builtin_amdgcn_s_sleep(1);
      }
      __syncthreads();
      __threadfence();  // acquire side: invalidate L1 before reading remote h

      // gather full h (16 rows x 512) into LDS
      for (int i = tid; i < RPC * 64; i += 256) {
        int rr = i >> 6, ch = (i & 63) * 8;
        *(ushort8*)&hlds[rr][ch] = *(const ushort8*)(hgp + rr * NH + ch);
      }
      __syncthreads();

      // w = M_slice @ h  (two 16x16 tiles per wave, K=512)
      f32x4 acc0 = {0.f, 0.f, 0.f, 0.f}, acc1 = {0.f, 0.f, 0.f, 0.f};
#pragma unroll
      for (int k0 = 0; k0 < NH; k0 += 32) {
        int kc = k0 + g4 * 8;
        short8 bf = *(const short8*)&hlds[r][kc];
        short8 a0 = *(const short8*)&Mlds[wv * 32 + r][kc];
        short8 a1 = *(const short8*)&Mlds[wv * 32 + 16 + r][kc];
        acc0 = __builtin_amdgcn_mfma_f32_16x16x32_bf16(a0, bf, acc0, 0, 0, 0);
        acc1 = __builtin_amdgcn_mfma_f32_16x16x32_bf16(a1, bf, acc1, 0, 0, 0);
      }
      float wc[2][4];
#pragma unroll
      for (int j = 0; j < 4; ++j) { wc[0][j] = acc0[j] + cr[0][j]; wc[1][j] = acc1[j] + cr[1][j]; }

      // RK4 bookkeeping
      float cw = (st == 0 || st == 3) ? 1.f : 2.f;
#pragma unroll
      for (int t = 0; t < 2; ++t)
#pragma unroll
        for (int j = 0; j < 4; ++j) {
          if (st == 0) { Wa[t][j] = wc[t][j]; Hs[t][j] = hr[t][j]; }
          else { Wa[t][j] += cw * wc[t][j]; Hs[t][j] += cw * hr[t][j]; }
          wp[t][j] = wc[t][j];
        }
      if (st == 3) {
        float f6 = dt * (1.f / 6.f);
#pragma unroll
        for (int t = 0; t < 2; ++t)
#pragma unroll
          for (int j = 0; j < 4; ++j) {
            u[t][j] += f6 * Wa[t][j];
            Ht[t][j] += f6 * Hs[t][j];
          }
      }
      // NOTE: no extra sync needed before next stage's hlds overwrite:
      // next stage's __syncthreads (after hG publish) orders all MFMA reads first.
    }
  }

  // write out H accumulator
#pragma unroll
  for (int t = 0; t < 2; ++t)
#pragma unroll
    for (int j = 0; j < 4; ++j)
      Hacc[(row0 + r) * NH + ub + udl0 + t * 16 + j] = Ht[t][j];
}

// -------------------- epilogue --------------------
// out[r][o] = bout[o] + sum_d Wout[o][d]*(y0[r][d] + sum_dt*b2[d]) + sum_h P[o][h]*Hacc[r][h]
__global__ void k_epi(const float* __restrict__ y0, const float* __restrict__ Hacc,
                      const float* __restrict__ P, const float* __restrict__ Wout,
                      const float* __restrict__ b2, const float* __restrict__ bout,
                      const float* __restrict__ dtsg, float* __restrict__ out)
{
  __shared__ float ys[NH], hs[NH];
  int rr = blockIdx.x, o = threadIdx.x;
  float sdt = dtsg[NS - 1];
  for (int i = threadIdx.x; i < NH; i += blockDim.x) {
    ys[i] = y0[rr * NH + i] + sdt * b2[i];
    hs[i] = Hacc[rr * NH + i];
  }
  __syncthreads();
  float s = bout[o];
  const float* wr = Wout + o * NH;
  const float* pr = P + o * NH;
  for (int d = 0; d < NH; ++d) s += wr[d] * ys[d];
  for (int h = 0; h < NH; ++h) s += pr[h] * hs[h];
  out[rr * NOUT + o] = s;
}

// -------------------- launch --------------------

extern "C" void kernel_launch(void* const* d_in, const int* in_sizes, int n_in,
                              void* d_out, int out_size, void* d_ws, size_t ws_size,
                              hipStream_t stream) {
  const float* x    = (const float*)d_in[0];
  const float* W1   = (const float*)d_in[1];
  const float* b1   = (const float*)d_in[2];
  const float* W2   = (const float*)d_in[3];
  const float* b2   = (const float*)d_in[4];
  const float* Wout = (const float*)d_in[5];
  const float* bout = (const float*)d_in[6];
  float* out = (float*)d_out;

  char* ws = (char*)d_ws;
  float*          dts  = (float*)(ws + OFF_DTS);
  float*          y0   = (float*)(ws + OFF_Y0);
  float*          u0   = (float*)(ws + OFF_U0);
  __hip_bfloat16* Mbf  = (__hip_bfloat16*)(ws + OFF_M);
  float*          cvec = (float*)(ws + OFF_C);
  float*          P    = (float*)(ws + OFF_P);
  __hip_bfloat16* hG   = (__hip_bfloat16*)(ws + OFF_HG);
  float*          Hac  = (float*)(ws + OFF_HACC);
  unsigned int*   flg  = (unsigned int*)(ws + OFF_FLAGS);

  hipMemsetAsync(flg, 0, NCL * 1024 * 4, stream);

  k_dts<<<1, 256, 0, stream>>>(x, dts);
  k_y0 <<<NB, 256, 0, stream>>>(x, y0);
  k_c  <<<2, 256, 0, stream>>>(W1, b2, cvec);
  // M = W1 @ W2 (512x512), bf16
  k_mm_nn_bf16<<<dim3(32, 32), 256, 0, stream>>>(W1, W2, Mbf, NH, NH);
  // u0 = y0 @ W1^T (256x512)
  k_mm_nt_f32<<<dim3(32, 16), 256, 0, stream>>>(y0, W1, u0, NH, NH);
  // P = Wout @ W2 (128x512)
  k_mm_nn_f32<<<dim3(32, 8), 256, 0, stream>>>(Wout, W2, P, NH, NH);

  k_main<<<NCL * BPC, 256, 0, stream>>>(u0, Mbf, cvec, b1, dts, hG, Hac, flg);

  k_epi<<<NB, NOUT, 0, stream>>>(y0, Hac, P, Wout, b2, bout, dts, out);
}

// Round 2
// 3144.887 us; speedup vs baseline: 5.3620x; 5.3620x over previous
//
#include <hip/hip_runtime.h>
#include <hip/hip_bf16.h>

typedef __attribute__((ext_vector_type(8))) short short8;
typedef __attribute__((ext_vector_type(8))) unsigned short ushort8;
typedef __attribute__((ext_vector_type(4))) float f32x4;
typedef __attribute__((ext_vector_type(4))) int int4v;
typedef __attribute__((ext_vector_type(4))) short short4v;

#define NB 256      // batch rows
#define NS 256      // timesteps
#define NH 512      // hidden/state dim (D == H == 512)
#define NOUT 128
#define XROW 513    // x last-dim stride

#define NCL 16      // clusters
#define RPC 16      // rows per cluster
#define BPC 4       // blocks per cluster
#define UBS 128     // u-dims per block
#define LPAD 520    // padded LDS row length (bf16): 1040B stride == 65 16B-slots (odd) -> even slot spread

// ---- workspace layout (bytes) ----
#define OFF_DTS   0                                  // 256 f32 (255 dts + sum_dt)
#define OFF_Y0    4096                               // 256*512 f32
#define OFF_U0    (OFF_Y0 + NB*NH*4)                 // 256*512 f32
#define OFF_M     (OFF_U0 + NB*NH*4)                 // 512*512 bf16
#define OFF_C     (OFF_M + NH*NH*2)                  // 512 f32 (c = W1@b2)
#define OFF_P     (OFF_C + 4096)                     // 128*512 f32 (P = Wout@W2)
#define OFF_HG    (OFF_P + NOUT*NH*4)                // 16 clusters * 2 buf * 16*512 bf16 h exchange
#define OFF_HACC  (OFF_HG + NCL*2*RPC*NH*2)         // 256*512 f32
#define OFF_FLAGS (OFF_HACC + NB*NH*4)              // 16 clusters * 4 u32 (monotonic), 64B-padded each

static __device__ __forceinline__ unsigned short bf16bits(float x) {
  return __builtin_bit_cast(unsigned short, __float2bfloat16(x));
}

// -------------------- small prep kernels --------------------

__global__ void k_dts(const float* __restrict__ x, float* __restrict__ dts) {
  int s = threadIdx.x;
  if (s < NS - 1) dts[s] = x[(s + 1) * XROW] - x[s * XROW];
  if (s == NS - 1) dts[NS - 1] = x[(NS - 1) * XROW] - x[0];  // sum_dt (telescoping)
}

__global__ void k_y0(const float* __restrict__ x, float* __restrict__ y0) {
  int b = blockIdx.x;
  const float* src = x + (size_t)b * NS * XROW + (size_t)(NS - 1) * XROW + 1;
  for (int d = threadIdx.x; d < NH; d += blockDim.x) y0[b * NH + d] = src[d];
}

__global__ void k_c(const float* __restrict__ W1, const float* __restrict__ b2,
                    float* __restrict__ c) {
  int i = blockIdx.x * blockDim.x + threadIdx.x;
  if (i < NH) {
    float s = 0.f;
    for (int d = 0; d < NH; ++d) s += W1[i * NH + d] * b2[d];
    c[i] = s;
  }
}

__global__ void k_mm_nn_bf16(const float* __restrict__ A, const float* __restrict__ Bm,
                             __hip_bfloat16* __restrict__ C, int N, int K) {
  __shared__ float As[16][17], Bs[16][17];
  int tx = threadIdx.x & 15, ty = threadIdx.x >> 4;
  int m = blockIdx.y * 16 + ty, n = blockIdx.x * 16 + tx;
  float acc = 0.f;
  for (int k0 = 0; k0 < K; k0 += 16) {
    As[ty][tx] = A[m * K + k0 + tx];
    Bs[ty][tx] = Bm[(size_t)(k0 + ty) * N + n];
    __syncthreads();
#pragma unroll
    for (int kk = 0; kk < 16; ++kk) acc += As[ty][kk] * Bs[kk][tx];
    __syncthreads();
  }
  C[m * N + n] = __float2bfloat16(acc);
}

__global__ void k_mm_nn_f32(const float* __restrict__ A, const float* __restrict__ Bm,
                            float* __restrict__ C, int N, int K) {
  __shared__ float As[16][17], Bs[16][17];
  int tx = threadIdx.x & 15, ty = threadIdx.x >> 4;
  int m = blockIdx.y * 16 + ty, n = blockIdx.x * 16 + tx;
  float acc = 0.f;
  for (int k0 = 0; k0 < K; k0 += 16) {
    As[ty][tx] = A[m * K + k0 + tx];
    Bs[ty][tx] = Bm[(size_t)(k0 + ty) * N + n];
    __syncthreads();
#pragma unroll
    for (int kk = 0; kk < 16; ++kk) acc += As[ty][kk] * Bs[kk][tx];
    __syncthreads();
  }
  C[m * N + n] = acc;
}

__global__ void k_mm_nt_f32(const float* __restrict__ A, const float* __restrict__ Bm,
                            float* __restrict__ C, int N, int K) {
  __shared__ float As[16][17], Bs[16][17];
  int tx = threadIdx.x & 15, ty = threadIdx.x >> 4;
  int m = blockIdx.y * 16 + ty;
  int n0 = blockIdx.x * 16;
  float acc = 0.f;
  for (int k0 = 0; k0 < K; k0 += 16) {
    As[ty][tx] = A[m * K + k0 + tx];
    Bs[ty][tx] = Bm[(size_t)(n0 + ty) * K + k0 + tx];
    __syncthreads();
#pragma unroll
    for (int kk = 0; kk < 16; ++kk) acc += As[ty][kk] * Bs[tx][kk];
    __syncthreads();
  }
  C[m * N + n0 + tx] = acc;
}

// -------------------- main ODE integration kernel --------------------
// 64 blocks = 16 clusters x 4 blocks. Cluster c owns rows [16c,16c+16);
// block j owns u-dims [128j,128j+128) with that M-slice in LDS.
// Cross-block h exchange goes through the LLC coherence point via sc0 sc1
// loads/stores -- NO fences, NO L2 writeback/invalidate. Flags are monotonic
// per-cluster per-producer words; release order = data stores -> vmcnt(0) ->
// barrier -> flag store; acquire order = flag poll -> vmcnt(0) -> data loads.

__global__ __launch_bounds__(256) void k_main(
    const float* __restrict__ u0, const __hip_bfloat16* __restrict__ Mg,
    const float* __restrict__ cg, const float* __restrict__ b1g,
    const float* __restrict__ dtsg,
    __hip_bfloat16* __restrict__ hG, float* __restrict__ Hacc,
    unsigned int* __restrict__ flags)
{
  __shared__ __hip_bfloat16 Mlds[UBS][LPAD];   // 130 KB
  __shared__ __hip_bfloat16 hlds[RPC][LPAD];   // 16.25 KB
  __shared__ float dtl[NS];

  const int tid = threadIdx.x;
  const int bx = blockIdx.x;
  const int cl = bx >> 2, jb = bx & 3;
  const int lane = tid & 63, wv = tid >> 6;
  const int r = lane & 15, g4 = lane >> 4;
  const int row0 = cl * RPC;
  const int ub = jb * UBS;

  // stage M slice into LDS (rows [ub, ub+128) of M)
  for (int i = tid; i < UBS * 64; i += 256) {
    int row = i >> 6, ch = (i & 63) * 8;
    *(ushort8*)&Mlds[row][ch] = *(const ushort8*)(Mg + (size_t)(ub + row) * NH + ch);
  }
  if (tid < NS) dtl[tid] = dtsg[tid];

  // per-lane state: (udim = ub + wv*32 + t*16 + g4*4 + j, batch row = row0 + r)
  const int udl0 = wv * 32 + g4 * 4;
  float u[2][4], Wa[2][4], Hs[2][4], Ht[2][4], hr[2][4], wp[2][4];
  float b1r[2][4], cr[2][4];
#pragma unroll
  for (int t = 0; t < 2; ++t)
#pragma unroll
    for (int j = 0; j < 4; ++j) {
      int ud = ub + udl0 + t * 16 + j;
      u[t][j] = u0[(row0 + r) * NH + ud];
      b1r[t][j] = b1g[ud];
      cr[t][j] = cg[ud];
      Ht[t][j] = 0.f; wp[t][j] = 0.f; Wa[t][j] = 0.f; Hs[t][j] = 0.f;
    }
  __syncthreads();

  unsigned int* flg = flags + cl * 16;   // 4 words used, 64B spacing per cluster
  unsigned int* myflag = flg + jb;

  int sidx = 0;
  for (int step = 0; step < NS - 1; ++step) {
    float dt = dtl[step];
#pragma unroll 1
    for (int st = 0; st < 4; ++st, ++sidx) {
      float gam = (st == 0) ? 0.f : ((st == 3) ? dt : 0.5f * dt);
      // h = tanh(u + gam*w_prev + b1)
#pragma unroll
      for (int t = 0; t < 2; ++t)
#pragma unroll
        for (int j = 0; j < 4; ++j)
          hr[t][j] = tanhf(u[t][j] + gam * wp[t][j] + b1r[t][j]);

      // publish own h slice to LLC (sc0 sc1 stores, 2x 8B per lane)
      int par = sidx & 1;
      __hip_bfloat16* hgp = hG + (size_t)(cl * 2 + par) * RPC * NH;
#pragma unroll
      for (int t = 0; t < 2; ++t) {
        short4v pk;
        pk.x = (short)bf16bits(hr[t][0]);
        pk.y = (short)bf16bits(hr[t][1]);
        pk.z = (short)bf16bits(hr[t][2]);
        pk.w = (short)bf16bits(hr[t][3]);
        const __hip_bfloat16* addr = hgp + r * NH + ub + udl0 + t * 16;
        asm volatile("global_store_dwordx2 %0, %1, off sc0 sc1"
                     :: "v"(addr), "v"(pk) : "memory");
      }
      asm volatile("s_waitcnt vmcnt(0)" ::: "memory");
      __syncthreads();
      if (tid == 0) {
        unsigned int tgt = (unsigned int)(sidx + 1);
        asm volatile("global_store_dword %0, %1, off sc0 sc1"
                     :: "v"(myflag), "v"(tgt) : "memory");
        // poll all 4 producer flags with one coherent 16B load
        int4v fv;
        for (;;) {
          asm volatile("global_load_dwordx4 %0, %1, off sc0 sc1\n\ts_waitcnt vmcnt(0)"
                       : "=v"(fv) : "v"(flg) : "memory");
          if ((unsigned)fv.x >= tgt && (unsigned)fv.y >= tgt &&
              (unsigned)fv.z >= tgt && (unsigned)fv.w >= tgt) break;
          __builtin_amdgcn_s_sleep(1);
        }
      }
      __syncthreads();

      // gather full h (16 rows x 512 bf16 = 16KB) via coherent loads into LDS
      {
        int4v dv[4];
        const char* hb = (const char*)hgp;
#pragma unroll
        for (int q = 0; q < 4; ++q) {
          int c = tid + 256 * q;
          int rr = c >> 6, cc = c & 63;
          const void* a = hb + rr * 1024 + cc * 16;
          asm volatile("global_load_dwordx4 %0, %1, off sc0 sc1"
                       : "=v"(dv[q]) : "v"(a) : "memory");
        }
        asm volatile("s_waitcnt vmcnt(0)" ::: "memory");
#pragma unroll
        for (int q = 0; q < 4; ++q) {
          int c = tid + 256 * q;
          int rr = c >> 6, cc = c & 63;
          *(int4v*)&hlds[rr][cc * 8] = dv[q];
        }
      }
      __syncthreads();

      // w = M_slice @ h  (two 16x16 tiles per wave, K=512)
      f32x4 acc0 = {0.f, 0.f, 0.f, 0.f}, acc1 = {0.f, 0.f, 0.f, 0.f};
#pragma unroll
      for (int k0 = 0; k0 < NH; k0 += 32) {
        int kc = k0 + g4 * 8;
        short8 bf = *(const short8*)&hlds[r][kc];
        short8 a0 = *(const short8*)&Mlds[wv * 32 + r][kc];
        short8 a1 = *(const short8*)&Mlds[wv * 32 + 16 + r][kc];
        acc0 = __builtin_amdgcn_mfma_f32_16x16x32_bf16(a0, bf, acc0, 0, 0, 0);
        acc1 = __builtin_amdgcn_mfma_f32_16x16x32_bf16(a1, bf, acc1, 0, 0, 0);
      }
      float wc[2][4];
#pragma unroll
      for (int j = 0; j < 4; ++j) { wc[0][j] = acc0[j] + cr[0][j]; wc[1][j] = acc1[j] + cr[1][j]; }

      // RK4 bookkeeping
      float cw = (st == 0 || st == 3) ? 1.f : 2.f;
#pragma unroll
      for (int t = 0; t < 2; ++t)
#pragma unroll
        for (int j = 0; j < 4; ++j) {
          if (st == 0) { Wa[t][j] = wc[t][j]; Hs[t][j] = hr[t][j]; }
          else { Wa[t][j] += cw * wc[t][j]; Hs[t][j] += cw * hr[t][j]; }
          wp[t][j] = wc[t][j];
        }
      if (st == 3) {
        float f6 = dt * (1.f / 6.f);
#pragma unroll
        for (int t = 0; t < 2; ++t)
#pragma unroll
          for (int j = 0; j < 4; ++j) {
            u[t][j] += f6 * Wa[t][j];
            Ht[t][j] += f6 * Hs[t][j];
          }
      }
    }
  }

  // write out H accumulator (plain stores: next-dispatch coherence is implicit)
#pragma unroll
  for (int t = 0; t < 2; ++t)
#pragma unroll
    for (int j = 0; j < 4; ++j)
      Hacc[(row0 + r) * NH + ub + udl0 + t * 16 + j] = Ht[t][j];
}

// -------------------- epilogue --------------------
__global__ void k_epi(const float* __restrict__ y0, const float* __restrict__ Hacc,
                      const float* __restrict__ P, const float* __restrict__ Wout,
                      const float* __restrict__ b2, const float* __restrict__ bout,
                      const float* __restrict__ dtsg, float* __restrict__ out)
{
  __shared__ float ys[NH], hs[NH];
  int rr = blockIdx.x, o = threadIdx.x;
  float sdt = dtsg[NS - 1];
  for (int i = threadIdx.x; i < NH; i += blockDim.x) {
    ys[i] = y0[rr * NH + i] + sdt * b2[i];
    hs[i] = Hacc[rr * NH + i];
  }
  __syncthreads();
  float s = bout[o];
  const float* wr = Wout + o * NH;
  const float* pr = P + o * NH;
  for (int d = 0; d < NH; ++d) s += wr[d] * ys[d];
  for (int h = 0; h < NH; ++h) s += pr[h] * hs[h];
  out[rr * NOUT + o] = s;
}

// -------------------- launch --------------------

extern "C" void kernel_launch(void* const* d_in, const int* in_sizes, int n_in,
                              void* d_out, int out_size, void* d_ws, size_t ws_size,
                              hipStream_t stream) {
  const float* x    = (const float*)d_in[0];
  const float* W1   = (const float*)d_in[1];
  const float* b1   = (const float*)d_in[2];
  const float* W2   = (const float*)d_in[3];
  const float* b2   = (const float*)d_in[4];
  const float* Wout = (const float*)d_in[5];
  const float* bout = (const float*)d_in[6];
  float* out = (float*)d_out;

  char* ws = (char*)d_ws;
  float*          dts  = (float*)(ws + OFF_DTS);
  float*          y0   = (float*)(ws + OFF_Y0);
  float*          u0   = (float*)(ws + OFF_U0);
  __hip_bfloat16* Mbf  = (__hip_bfloat16*)(ws + OFF_M);
  float*          cvec = (float*)(ws + OFF_C);
  float*          P    = (float*)(ws + OFF_P);
  __hip_bfloat16* hG   = (__hip_bfloat16*)(ws + OFF_HG);
  float*          Hac  = (float*)(ws + OFF_HACC);
  unsigned int*   flg  = (unsigned int*)(ws + OFF_FLAGS);

  hipMemsetAsync(flg, 0, NCL * 16 * 4, stream);

  k_dts<<<1, 256, 0, stream>>>(x, dts);
  k_y0 <<<NB, 256, 0, stream>>>(x, y0);
  k_c  <<<2, 256, 0, stream>>>(W1, b2, cvec);
  k_mm_nn_bf16<<<dim3(32, 32), 256, 0, stream>>>(W1, W2, Mbf, NH, NH);
  k_mm_nt_f32<<<dim3(32, 16), 256, 0, stream>>>(y0, W1, u0, NH, NH);
  k_mm_nn_f32<<<dim3(32, 8), 256, 0, stream>>>(Wout, W2, P, NH, NH);

  k_main<<<NCL * BPC, 256, 0, stream>>>(u0, Mbf, cvec, b1, dts, hG, Hac, flg);

  k_epi<<<NB, NOUT, 0, stream>>>(y0, Hac, P, Wout, b2, bout, dts, out);
}

// Round 4
// 2696.308 us; speedup vs baseline: 6.2541x; 1.1664x over previous
//
#include <hip/hip_runtime.h>
#include <hip/hip_bf16.h>

typedef __attribute__((ext_vector_type(8))) short short8;
typedef __attribute__((ext_vector_type(8))) unsigned short ushort8;
typedef __attribute__((ext_vector_type(4))) float f32x4;
typedef __attribute__((ext_vector_type(4))) int int4v;
typedef __attribute__((ext_vector_type(4))) short short4v;

#define NB 256      // batch rows
#define NS 256      // timesteps
#define NH 512      // hidden/state dim (D == H == 512)
#define NOUT 128
#define XROW 513    // x last-dim stride

#define NCL 16      // clusters
#define RPC 16      // rows per cluster
#define BPC 4       // blocks per cluster
#define UBS 128     // u-dims per block
#define LPAD 520    // padded LDS row (bf16): 1040B stride -> rows spread across banks

// ---- workspace layout (bytes) ----
#define OFF_DTS   0
#define OFF_Y0    4096
#define OFF_U0    (OFF_Y0 + NB*NH*4)
#define OFF_M     (OFF_U0 + NB*NH*4)
#define OFF_C     (OFF_M + NH*NH*2)
#define OFF_P     (OFF_C + 4096)
#define OFF_HG    (OFF_P + NOUT*NH*4)                // 16 cl * 2 buf * 16*512 bf16
#define OFF_HACC  (OFF_HG + NCL*2*RPC*NH*2)
#define OFF_FLAGS (OFF_HACC + NB*NH*4)               // 16 cl * 128B: 16 wave flags each

static __device__ __forceinline__ unsigned short bf16bits(float x) {
  return __builtin_bit_cast(unsigned short, __float2bfloat16(x));
}

// All cross-block traffic: sc0 sc1 (LLC/HBM coherence point) — PROVEN in R2.
static __device__ __forceinline__ void g_store8(void* addr, short4v v) {
  asm volatile("global_store_dwordx2 %0, %1, off sc0 sc1" :: "v"(addr), "v"(v) : "memory");
}
static __device__ __forceinline__ void g_store4(void* addr, unsigned v) {
  asm volatile("global_store_dword %0, %1, off sc0 sc1" :: "v"(addr), "v"(v) : "memory");
}
static __device__ __forceinline__ unsigned g_load4w(const void* addr) {  // load + wait
  unsigned v;
  asm volatile("global_load_dword %0, %1, off sc0 sc1\n\ts_waitcnt vmcnt(0)"
               : "=v"(v) : "v"(addr) : "memory");
  return v;
}
static __device__ __forceinline__ int4v g_load16(const void* addr) {  // no wait
  int4v v;
  asm volatile("global_load_dwordx4 %0, %1, off sc0 sc1" : "=v"(v) : "v"(addr) : "memory");
  return v;
}
static __device__ __forceinline__ void wait_vm0() {
  asm volatile("s_waitcnt vmcnt(0)" ::: "memory");
}

// fast tanh: (e^{2x}-1)/(e^{2x}+1), clamp |x|<=15 so e^{2x} finite
static __device__ __forceinline__ float tanh_fast(float x) {
  x = fminf(fmaxf(x, -15.f), 15.f);
  float e = __expf(2.f * x);
  return (e - 1.f) * __builtin_amdgcn_rcpf(e + 1.f);
}

// -------------------- small prep kernels --------------------

__global__ void k_dts(const float* __restrict__ x, float* __restrict__ dts) {
  int s = threadIdx.x;
  if (s < NS - 1) dts[s] = x[(s + 1) * XROW] - x[s * XROW];
  if (s == NS - 1) dts[NS - 1] = x[(NS - 1) * XROW] - x[0];  // sum_dt (telescoping)
}

__global__ void k_y0(const float* __restrict__ x, float* __restrict__ y0) {
  int b = blockIdx.x;
  const float* src = x + (size_t)b * NS * XROW + (size_t)(NS - 1) * XROW + 1;
  for (int d = threadIdx.x; d < NH; d += blockDim.x) y0[b * NH + d] = src[d];
}

__global__ void k_c(const float* __restrict__ W1, const float* __restrict__ b2,
                    float* __restrict__ c) {
  int i = blockIdx.x * blockDim.x + threadIdx.x;
  if (i < NH) {
    float s = 0.f;
    for (int d = 0; d < NH; ++d) s += W1[i * NH + d] * b2[d];
    c[i] = s;
  }
}

__global__ void k_mm_nn_bf16(const float* __restrict__ A, const float* __restrict__ Bm,
                             __hip_bfloat16* __restrict__ C, int N, int K) {
  __shared__ float As[16][17], Bs[16][17];
  int tx = threadIdx.x & 15, ty = threadIdx.x >> 4;
  int m = blockIdx.y * 16 + ty, n = blockIdx.x * 16 + tx;
  float acc = 0.f;
  for (int k0 = 0; k0 < K; k0 += 16) {
    As[ty][tx] = A[m * K + k0 + tx];
    Bs[ty][tx] = Bm[(size_t)(k0 + ty) * N + n];
    __syncthreads();
#pragma unroll
    for (int kk = 0; kk < 16; ++kk) acc += As[ty][kk] * Bs[kk][tx];
    __syncthreads();
  }
  C[m * N + n] = __float2bfloat16(acc);
}

__global__ void k_mm_nn_f32(const float* __restrict__ A, const float* __restrict__ Bm,
                            float* __restrict__ C, int N, int K) {
  __shared__ float As[16][17], Bs[16][17];
  int tx = threadIdx.x & 15, ty = threadIdx.x >> 4;
  int m = blockIdx.y * 16 + ty, n = blockIdx.x * 16 + tx;
  float acc = 0.f;
  for (int k0 = 0; k0 < K; k0 += 16) {
    As[ty][tx] = A[m * K + k0 + tx];
    Bs[ty][tx] = Bm[(size_t)(k0 + ty) * N + n];
    __syncthreads();
#pragma unroll
    for (int kk = 0; kk < 16; ++kk) acc += As[ty][kk] * Bs[kk][tx];
    __syncthreads();
  }
  C[m * N + n] = acc;
}

__global__ void k_mm_nt_f32(const float* __restrict__ A, const float* __restrict__ Bm,
                            float* __restrict__ C, int N, int K) {
  __shared__ float As[16][17], Bs[16][17];
  int tx = threadIdx.x & 15, ty = threadIdx.x >> 4;
  int m = blockIdx.y * 16 + ty;
  int n0 = blockIdx.x * 16;
  float acc = 0.f;
  for (int k0 = 0; k0 < K; k0 += 16) {
    As[ty][tx] = A[m * K + k0 + tx];
    Bs[ty][tx] = Bm[(size_t)(n0 + ty) * K + k0 + tx];
    __syncthreads();
#pragma unroll
    for (int kk = 0; kk < 16; ++kk) acc += As[ty][kk] * Bs[tx][kk];
    __syncthreads();
  }
  C[m * N + n0 + tx] = acc;
}

// -------------------- main ODE integration kernel --------------------
// 64 blocks = 16 clusters x 4 blocks (bid remapped so a cluster's blocks share
// bid mod 8 -> likely same XCD; perf heuristic only, correctness independent).
// Per stage:
//   fast-tanh -> publish own h (sc0sc1 global + LDS) -> vmcnt(0) -> per-wave
//   flag store -> barrier -> own-k MFMA (overlaps peer flag flight) ->
//   all-lane flag poll -> gather 3 remote 4KB chunks -> barrier ->
//   remote-k MFMA -> RK4 tail.  2 barriers/stage, 0 atomics.

__global__ __launch_bounds__(256) void k_main(
    const float* __restrict__ u0, const __hip_bfloat16* __restrict__ Mg,
    const float* __restrict__ cg, const float* __restrict__ b1g,
    const float* __restrict__ dtsg,
    __hip_bfloat16* __restrict__ hG, float* __restrict__ Hacc,
    unsigned int* __restrict__ flags)
{
  __shared__ __hip_bfloat16 Mlds[UBS][LPAD];   // 130 KB
  __shared__ __hip_bfloat16 hlds[RPC][LPAD];   // 16.25 KB
  __shared__ float dtl[NS];

  const int tid = threadIdx.x;
  const int bx = blockIdx.x;
  const int xcd = bx & 7, slot = bx >> 3;
  const int cl = xcd + ((slot >> 2) << 3);
  const int jb = slot & 3;
  const int lane = tid & 63, wv = tid >> 6;
  const int r = lane & 15, g4 = lane >> 4;
  const int row0 = cl * RPC;
  const int ub = jb * UBS;

  // stage M slice into LDS (rows [ub, ub+128) of M)
  for (int i = tid; i < UBS * 64; i += 256) {
    int row = i >> 6, ch = (i & 63) * 8;
    *(ushort8*)&Mlds[row][ch] = *(const ushort8*)(Mg + (size_t)(ub + row) * NH + ch);
  }
  if (tid < NS) dtl[tid] = dtsg[tid];

  // per-lane state: (udim = ub + wv*32 + t*16 + g4*4 + j, batch row = row0 + r)
  const int udl0 = wv * 32 + g4 * 4;
  float u[2][4], Wa[2][4], Hs[2][4], Ht[2][4], hr[2][4], wp[2][4];
  float b1r[2][4], cr[2][4];
#pragma unroll
  for (int t = 0; t < 2; ++t)
#pragma unroll
    for (int j = 0; j < 4; ++j) {
      int ud = ub + udl0 + t * 16 + j;
      u[t][j] = u0[(row0 + r) * NH + ud];
      b1r[t][j] = b1g[ud];
      cr[t][j] = cg[ud];
      Ht[t][j] = 0.f; wp[t][j] = 0.f; Wa[t][j] = 0.f; Hs[t][j] = 0.f;
    }
  __syncthreads();

  unsigned int* flg = flags + cl * 32;   // 16 wave-flag words per cluster

  int sidx = 0;
  for (int step = 0; step < NS - 1; ++step) {
    float dt = dtl[step];
#pragma unroll 1
    for (int st = 0; st < 4; ++st, ++sidx) {
      float gam = (st == 0) ? 0.f : ((st == 3) ? dt : 0.5f * dt);
      // h = tanh(u + gam*w_prev + b1)  (fast tanh, serial critical path)
#pragma unroll
      for (int t = 0; t < 2; ++t)
#pragma unroll
        for (int j = 0; j < 4; ++j)
          hr[t][j] = tanh_fast(u[t][j] + gam * wp[t][j] + b1r[t][j]);

      int par = sidx & 1;
      __hip_bfloat16* hgp = hG + (size_t)(cl * 2 + par) * RPC * NH;
      // publish own h (global for peers, LDS for own-k MFMA)
#pragma unroll
      for (int t = 0; t < 2; ++t) {
        short4v pk;
        pk.x = (short)bf16bits(hr[t][0]);
        pk.y = (short)bf16bits(hr[t][1]);
        pk.z = (short)bf16bits(hr[t][2]);
        pk.w = (short)bf16bits(hr[t][3]);
        int col = ub + udl0 + t * 16;
        g_store8(hgp + r * NH + col, pk);
        *(short4v*)&hlds[r][col] = pk;
      }
      wait_vm0();                          // release: data ack'd at coherence pt
      unsigned tgt = (unsigned)(sidx + 1);
      if (lane == 0) g_store4(flg + jb * 4 + wv, tgt);   // per-wave flag
      __syncthreads();                     // own h visible in LDS to all waves

      // own-k MFMA (overlaps peers' flag/data flight)
      f32x4 acc0 = {0.f, 0.f, 0.f, 0.f}, acc1 = {0.f, 0.f, 0.f, 0.f};
#pragma unroll
      for (int q = 0; q < 4; ++q) {
        int kc = ub + q * 32 + g4 * 8;
        short8 bf = *(const short8*)&hlds[r][kc];
        short8 a0 = *(const short8*)&Mlds[wv * 32 + r][kc];
        short8 a1 = *(const short8*)&Mlds[wv * 32 + 16 + r][kc];
        acc0 = __builtin_amdgcn_mfma_f32_16x16x32_bf16(a0, bf, acc0, 0, 0, 0);
        acc1 = __builtin_amdgcn_mfma_f32_16x16x32_bf16(a1, bf, acc1, 0, 0, 0);
      }

      // all-lane poll of the 16 wave-flags
      {
        const unsigned int* fp = flg + (lane & 15);
        for (;;) {
          unsigned v = g_load4w(fp);
          if (__all((int)(v >= tgt))) break;
          __builtin_amdgcn_s_sleep(1);
        }
      }

      // gather 3 remote 4KB chunks into LDS
      {
        int rr = tid >> 4, sl = tid & 15;
        int4v dv[3];
#pragma unroll
        for (int m = 0; m < 3; ++m) {
          int jr = (jb + 1 + m) & 3;
          dv[m] = g_load16(hgp + rr * NH + jr * UBS + sl * 8);
        }
        wait_vm0();
#pragma unroll
        for (int m = 0; m < 3; ++m) {
          int jr = (jb + 1 + m) & 3;
          *(int4v*)&hlds[rr][jr * UBS + sl * 8] = dv[m];
        }
      }
      __syncthreads();

      // remote-k MFMA
#pragma unroll 1
      for (int m = 0; m < 3; ++m) {
        int jr = (jb + 1 + m) & 3;
#pragma unroll
        for (int q = 0; q < 4; ++q) {
          int kc = jr * UBS + q * 32 + g4 * 8;
          short8 bf = *(const short8*)&hlds[r][kc];
          short8 a0 = *(const short8*)&Mlds[wv * 32 + r][kc];
          short8 a1 = *(const short8*)&Mlds[wv * 32 + 16 + r][kc];
          acc0 = __builtin_amdgcn_mfma_f32_16x16x32_bf16(a0, bf, acc0, 0, 0, 0);
          acc1 = __builtin_amdgcn_mfma_f32_16x16x32_bf16(a1, bf, acc1, 0, 0, 0);
        }
      }

      float wc[2][4];
#pragma unroll
      for (int j = 0; j < 4; ++j) { wc[0][j] = acc0[j] + cr[0][j]; wc[1][j] = acc1[j] + cr[1][j]; }

      // RK4 bookkeeping
      float cw = (st == 0 || st == 3) ? 1.f : 2.f;
#pragma unroll
      for (int t = 0; t < 2; ++t)
#pragma unroll
        for (int j = 0; j < 4; ++j) {
          if (st == 0) { Wa[t][j] = wc[t][j]; Hs[t][j] = hr[t][j]; }
          else { Wa[t][j] += cw * wc[t][j]; Hs[t][j] += cw * hr[t][j]; }
          wp[t][j] = wc[t][j];
        }
      if (st == 3) {
        float f6 = dt * (1.f / 6.f);
#pragma unroll
        for (int t = 0; t < 2; ++t)
#pragma unroll
          for (int j = 0; j < 4; ++j) {
            u[t][j] += f6 * Wa[t][j];
            Ht[t][j] += f6 * Hs[t][j];
          }
      }
    }
  }

  // write out H accumulator
#pragma unroll
  for (int t = 0; t < 2; ++t)
#pragma unroll
    for (int j = 0; j < 4; ++j)
      Hacc[(row0 + r) * NH + ub + udl0 + t * 16 + j] = Ht[t][j];
}

// -------------------- epilogue --------------------
__global__ void k_epi(const float* __restrict__ y0, const float* __restrict__ Hacc,
                      const float* __restrict__ P, const float* __restrict__ Wout,
                      const float* __restrict__ b2, const float* __restrict__ bout,
                      const float* __restrict__ dtsg, float* __restrict__ out)
{
  __shared__ float ys[NH], hs[NH];
  int rr = blockIdx.x, o = threadIdx.x;
  float sdt = dtsg[NS - 1];
  for (int i = threadIdx.x; i < NH; i += blockDim.x) {
    ys[i] = y0[rr * NH + i] + sdt * b2[i];
    hs[i] = Hacc[rr * NH + i];
  }
  __syncthreads();
  float s = bout[o];
  const float* wr = Wout + o * NH;
  const float* pr = P + o * NH;
  for (int d = 0; d < NH; ++d) s += wr[d] * ys[d];
  for (int h = 0; h < NH; ++h) s += pr[h] * hs[h];
  out[rr * NOUT + o] = s;
}

// -------------------- launch --------------------

extern "C" void kernel_launch(void* const* d_in, const int* in_sizes, int n_in,
                              void* d_out, int out_size, void* d_ws, size_t ws_size,
                              hipStream_t stream) {
  const float* x    = (const float*)d_in[0];
  const float* W1   = (const float*)d_in[1];
  const float* b1   = (const float*)d_in[2];
  const float* W2   = (const float*)d_in[3];
  const float* b2   = (const float*)d_in[4];
  const float* Wout = (const float*)d_in[5];
  const float* bout = (const float*)d_in[6];
  float* out = (float*)d_out;

  char* ws = (char*)d_ws;
  float*          dts  = (float*)(ws + OFF_DTS);
  float*          y0   = (float*)(ws + OFF_Y0);
  float*          u0   = (float*)(ws + OFF_U0);
  __hip_bfloat16* Mbf  = (__hip_bfloat16*)(ws + OFF_M);
  float*          cvec = (float*)(ws + OFF_C);
  float*          P    = (float*)(ws + OFF_P);
  __hip_bfloat16* hG   = (__hip_bfloat16*)(ws + OFF_HG);
  float*          Hac  = (float*)(ws + OFF_HACC);
  unsigned int*   flg  = (unsigned int*)(ws + OFF_FLAGS);

  hipMemsetAsync(flg, 0, NCL * 32 * 4, stream);

  k_dts<<<1, 256, 0, stream>>>(x, dts);
  k_y0 <<<NB, 256, 0, stream>>>(x, y0);
  k_c  <<<2, 256, 0, stream>>>(W1, b2, cvec);
  k_mm_nn_bf16<<<dim3(32, 32), 256, 0, stream>>>(W1, W2, Mbf, NH, NH);
  k_mm_nt_f32<<<dim3(32, 16), 256, 0, stream>>>(y0, W1, u0, NH, NH);
  k_mm_nn_f32<<<dim3(32, 8), 256, 0, stream>>>(Wout, W2, P, NH, NH);

  k_main<<<NCL * BPC, 256, 0, stream>>>(u0, Mbf, cvec, b1, dts, hG, Hac, flg);

  k_epi<<<NB, NOUT, 0, stream>>>(y0, Hac, P, Wout, b2, bout, dts, out);
}